// Round 16
// baseline (276.498 us; speedup 1.0000x reference)
//
#include <hip/hip_runtime.h>
#include <cstdint>
#include <math.h>

#define BATCH    65536
#define HIS_LEN  5
#define KIND_LEN 10
#define SB       64    // samples per block
#define NTH      256   // threads per block (4 waves); 4 threads per sample

typedef float    v2f __attribute__((ext_vector_type(2)));
typedef float    v4f __attribute__((ext_vector_type(4)));
typedef _Float16 v2h __attribute__((ext_vector_type(2)));
typedef _Float16 v8h __attribute__((ext_vector_type(8)));
__device__ __forceinline__ v2f mk2(float a, float b){ v2f r; r.x=a; r.y=b; return r; }
#define C2H(u)  __builtin_bit_cast(v2h,(unsigned)(u))
#define C8H(u4) __builtin_bit_cast(v8h,(u4))

#if __has_builtin(__builtin_amdgcn_fdot2)
__device__ __forceinline__ float FD2(v2h a, v2h b, float c){
  return __builtin_amdgcn_fdot2(a, b, c, false);
}
#else
__device__ __forceinline__ float FD2(v2h a, v2h b, float c){
  return c + (float)a.x*(float)b.x + (float)a.y*(float)b.y;
}
#endif

__device__ __forceinline__ unsigned short f2h(float f){
  return __builtin_bit_cast(unsigned short, (_Float16)f);
}
__device__ __forceinline__ unsigned pack2h(float a, float b){
  return (unsigned)f2h(a) | ((unsigned)f2h(b) << 16);
}
__device__ __forceinline__ v2h pkh(float a, float b){
  return __builtin_bit_cast(v2h, __builtin_amdgcn_cvt_pkrtz(a, b));
}

// ---- ws layout (dword offsets) ----
#define OFF_HW1F 0      // 6144: hist W1 B-frags [4n][6t][64 lane][4dw], K=192=[i1|i2]
#define OFF_AW2F 6144   // 1024: act W2 B-frags [2n2][2t2][64][4]
#define OFF_PF   7168   // 258: AB1 64|AB2 32|W3 32|AB3 1|MB2 64|MB3 32|M4 32|MB4 1
#define OFF_M3H  7428   // 1024: tail M3 f16 pairs [4q][8ip][32dw]
#define OFF_MW1F 8452   // 14336: MLP W1 B-frags [8n][7t][64][4]
#define OFF_MB1  22788  // 128
#define OFF_MW2F 22916  // 4096: MLP W2 B-frags [4n2][4t2][64][4]
#define PREP_N   27012
// f4 indices into ws
#define AW2F4 1536
#define M3H4  1857
#define MW1F4 2113
#define MW2F4 5729

// ---- LDS layout (f4 units unless noted) — 37.4 KB -> 4 blocks/CU ----
#define X2B   0        // i2 features [64][13 f4]
#define X1B   832      // i1 features per step [64][13 f4]
#define H1B   1664     // hist hidden f16 [64][9 f4]   (2240 f4 total)
#define M3HL  1664     // MLP-phase reuse: tail weights (skewed q*66), 262 f4
#define LAB1  8960
#define LAB2  9024
#define LW3   9056
#define LAB3  9088
#define LMB2  9089
#define LMB3  9153
#define LM4   9185
#define LMB4  9217
#define MB1F  9220
#define LDSF  9348
// MLP phase reuses f4 [0,1856): X-MLP [64][29]; then H1-MLP [0,1088) s17,
// H2-MLP [1088,1664) s9; M3H staged at [1664,1926) after BAR-M2.

typedef const float* fp;

__device__ __forceinline__ float m1s_val(fp m1, int o, int q, int t){
  if(t >= 52) return 0.f;
  int src;
  if(t<8){ int E = (q==0)?0:(8+8*q); src = E + t; }
  else if(t<30){ int d=t-8; int idx = 8*(d>>1)+2*q+(d&1);
                 src = (idx<8) ? (8+idx) : (32+idx); }
  else { int d=t-30; int idx = 8*(d>>1)+2*q+(d&1); src = 120+idx; }
  return m1[o*208 + src];
}
__device__ __forceinline__ float m1k(fp m1, int o, int k){
  return m1s_val(m1, o, k/56, k%56);
}
__device__ __forceinline__ float w1c_val(fp aw1, int o, int q, int h, int d){
  if(d >= 22) return 0.f;
  int idx = 8*(d>>1) + 2*q + (d&1);
  return h ? (aw1[o*264+176+idx] - aw1[o*264+88+idx])
           : (aw1[o*264+idx]     + aw1[o*264+88+idx]);
}
__device__ __forceinline__ float hw1v(fp aw1, int o, int k){
  int h = (k >= 96) ? 1 : 0;
  int kk = k - 96*h;
  int q = kk/24, d = kk%24;
  return (d<22) ? w1c_val(aw1,o,q,h,d) : 0.f;
}

__global__ void din_prep(fp aw1, fp ab1, fp aw2, fp ab2, fp aw3, fp ab3,
                         fp m1,  fp mb1, fp m2,  fp mb2, fp m3,  fp mb3,
                         fp m4,  fp mb4, float* __restrict__ ws){
  int j = blockIdx.x*blockDim.x + threadIdx.x;
  unsigned* wsu = (unsigned*)ws;
  if(j < 6144){ // HW1F: [4n][6t][64][4]
    int frag = j>>2, jr = j&3;
    int lane = frag & 63, nt = frag >> 6;
    int n = nt/6, t = nt%6;
    int o = 16*n + (lane&15);
    int k0 = t*32 + ((lane>>4)<<3) + 2*jr;
    wsu[OFF_HW1F + j] = pack2h(hw1v(aw1,o,k0), hw1v(aw1,o,k0+1));
    return;
  } j -= 6144;
  if(j < 1024){ // AW2F: [2n2][2t2][64][4]
    int frag = j>>2, jr = j&3;
    int lane = frag & 63, nt = frag >> 6;
    int n2 = nt>>1, t2 = nt&1;
    int o = 16*n2 + (lane&15);
    int k0 = t2*32 + ((lane>>4)<<3) + 2*jr;
    wsu[OFF_AW2F + j] = pack2h(aw2[o*64 + k0], aw2[o*64 + k0+1]);
    return;
  } j -= 1024;
  if(j < 258){ // PF
    float v;
    if(j < 64)       v = ab1[j];
    else if(j < 96)  v = ab2[j-64];
    else if(j < 128) v = aw3[j-96];
    else if(j < 129) v = ab3[0];
    else if(j < 193) v = mb2[j-129];
    else if(j < 225) v = mb3[j-193];
    else if(j < 257) v = m4[j-225];
    else             v = mb4[0];
    ws[OFF_PF + j] = v; return;
  } j -= 258;
  if(j < 2){ ws[OFF_PF+258+j] = 0.f; return; } j -= 2;
  if(j < 1024){ // M3H
    int qq = j>>8, rr = j&255, ip = rr>>5, dw = rr&31;
    wsu[OFF_M3H + j] = pack2h(m3[dw*64 + 16*qq + 2*ip], m3[dw*64 + 16*qq + 2*ip+1]);
    return;
  } j -= 1024;
  if(j < 14336){ // MW1F
    int frag = j>>2, jr = j&3;
    int lane = frag & 63, nt = frag >> 6;
    int n = nt/7, t = nt - 7*n;
    int o = 16*n + (lane&15);
    int k0 = t*32 + ((lane>>4)<<3) + 2*jr;
    wsu[OFF_MW1F + j] = pack2h(m1k(m1,o,k0), m1k(m1,o,k0+1));
    return;
  } j -= 14336;
  if(j < 128){ ws[OFF_MB1 + j] = mb1[j]; return; } j -= 128;
  if(j < 4096){ // MW2F
    int frag = j>>2, jr = j&3;
    int lane = frag & 63, nt = frag >> 6;
    int n2 = nt>>2, t2 = nt&3;
    int o = 16*n2 + (lane&15);
    int k0 = t2*32 + ((lane>>4)<<3) + 2*jr;
    wsu[OFF_MW2F + j] = pack2h(m2[o*128 + k0], m2[o*128 + k0+1]);
    return;
  }
}

// DPP quad reduction
template<int CTL>
__device__ __forceinline__ float qp(float v){
  return __uint_as_float((unsigned)__builtin_amdgcn_update_dpp(
      0, (int)__float_as_uint(v), CTL, 0xF, 0xF, true));
}
__device__ __forceinline__ float bsum4(float v){
  v += qp<0xB1>(v);
  v += qp<0x4E>(v);
  return v;
}
// reduce across 16-lane row: xor1,2 via DPP; xor4,8 via shfl
__device__ __forceinline__ float rsum16(float v){
  v += qp<0xB1>(v);
  v += qp<0x4E>(v);
  v += __shfl_xor(v, 4);
  v += __shfl_xor(v, 8);
  return v;
}

__device__ __forceinline__ void ldst16(void* l, const void* g){
  __builtin_amdgcn_global_load_lds(
      (const __attribute__((address_space(1))) unsigned int*)(uintptr_t)g,
      (__attribute__((address_space(3))) unsigned int*)(uintptr_t)l, 16, 0, 0);
}
__device__ __forceinline__ void ldst4(void* l, const void* g){
  __builtin_amdgcn_global_load_lds(
      (const __attribute__((address_space(1))) unsigned int*)(uintptr_t)g,
      (__attribute__((address_space(3))) unsigned int*)(uintptr_t)l, 4, 0, 0);
}

__device__ __forceinline__ void gather_h(const float2* __restrict__ itemp,
                                         const float2* __restrict__ kindp,
                                         int item_idx, const int* __restrict__ kidx,
                                         int q, v2h* f){
  float2 v = itemp[item_idx*4 + q];
  f[0] = pkh(v.x, v.y);
  #pragma unroll
  for(int r=0;r<KIND_LEN;r++){
    int ki = kidx[r];
    float2 w = kindp[ki*4 + q];
    float mx = ki ? w.x : 0.f, my = ki ? w.y : 0.f;
    f[1+r] = pkh(mx, my);
  }
}

__device__ __forceinline__ void write_X(float4* ls4, int base, int wid, int q,
                                        const v2h* f){
  unsigned xd[12];
  #pragma unroll
  for(int r=0;r<11;r++) xd[r] = __builtin_bit_cast(unsigned, f[r]);
  xd[11] = 0;
  uint4* xp = (uint4*)(ls4 + base + wid*13 + 3*q);
  #pragma unroll
  for(int c=0;c<3;c++){
    uint4 t; t.x=xd[4*c]; t.y=xd[4*c+1]; t.z=xd[4*c+2]; t.w=xd[4*c+3];
    xp[c] = t;
  }
}

// 256 threads; 64 samples/block; history+MLP via MFMA. R11 barrier skeleton;
// hist act-tail fully in-register (no H2 region), M3H staged in MLP phase:
// LDS 37.4 KB -> 4 blocks/CU. launch_bounds min=3 so the allocator may use
// up to ~170 VGPR (expect ~90-110, <=128 keeps 4 waves/SIMD runtime occ).
__global__ void __launch_bounds__(NTH, 3)
din_main(const int* __restrict__ userid, const int* __restrict__ itemid,
         const int* __restrict__ age,    const int* __restrict__ gen,
         const int* __restrict__ occ,    const int* __restrict__ item_kind,
         const int* __restrict__ his_id, const int* __restrict__ his_kind,
         const float2* __restrict__ user_emb, const float2* __restrict__ item_emb,
         const float2* __restrict__ age_emb,  const float2* __restrict__ gen_emb,
         const float2* __restrict__ occ_emb,  const float2* __restrict__ kind_emb,
         const float* __restrict__ ws, float* __restrict__ out){
  const int tid  = threadIdx.x;
  const int q    = tid & 3;
  const int sl   = (tid & 63) >> 2;
  const int wv   = __builtin_amdgcn_readfirstlane(tid >> 6);
  const int wid  = wv*16 + sl;                 // sample-in-block 0..63
  const int b    = blockIdx.x*SB + wid;
  const int l    = tid & 63;
  const int sr   = wv*16 + (l&15);             // MFMA A-row (sample)
  const int kb   = l >> 4;                     // MFMA K-chunk 0..3

  __shared__ __align__(16) float ls[LDSF];
  float4* ls4 = (float4*)ls;
  const uint4* lsu4 = (const uint4*)ls;
  const float* wsc = ws;
  const float4* ws4 = (const float4*)ws;
  const uint4* wsu4 = (const uint4*)ws;

  // ---- initial async staging: PF(258) + MB1(128) ----
  ldst4(ls + LAB1 + tid, wsc + OFF_PF + tid);
  if(tid < 2)   ldst4(ls + LAB1 + 256 + tid, wsc + OFF_PF + 256 + tid);
  if(tid < 128) ldst4(ls + MB1F + tid, wsc + OFF_MB1 + tid);

  // ---- gather i2 -> X2 (persistent K-tiles 3..5) ----
  {
    v2h i2t[11];
    gather_h(item_emb, kind_emb, itemid[b], item_kind + b*KIND_LEN, q, i2t);
    write_X(ls4, X2B, wid, q, i2t);
  }
  // ---- gather step-0 i1 ----
  v2h i1c[11], i1n[11];
  gather_h(item_emb, kind_emb, his_id[b*HIS_LEN], his_kind + b*HIS_LEN*KIND_LEN,
           q, i1c);

  v2f poolv[11];
  #pragma unroll
  for(int d=0;d<11;d++) poolv[d]=mk2(0.f,0.f);
  v2h i2h[11];
  float2 exr[4];

  __syncthreads();   // BAR-0: staging + X2 drained

  // ---- hoisted loop-invariants ----
  float hb1[4], hb2[2];
  #pragma unroll
  for(int n=0;n<4;n++)  hb1[n] = ls[LAB1 + 16*n + (l&15)];
  #pragma unroll
  for(int n2=0;n2<2;n2++) hb2[n2] = ls[LAB2 + 16*n2 + (l&15)];
  const float w3a = ls[LW3 + (l&15)];
  const float w3b = ls[LW3 + 16 + (l&15)];
  const float ab3v = ls[LAB3];
  const int ii = (l>>2)&3;   // which C-row slot this thread's sample maps to

  // ---- history: 5 steps, MFMA act-unit, in-register score ----
  #pragma unroll 1
  for(int s=0;s<5;s++){
    write_X(ls4, X1B, wid, q, i1c);
    __syncthreads();                       // BAR1: X1 ready
    if(s < 4){
      gather_h(item_emb, kind_emb, his_id[b*HIS_LEN+s+1],
               his_kind + (b*HIS_LEN+s+1)*KIND_LEN, q, i1n);
    } else {
      gather_h(item_emb, kind_emb, itemid[b], item_kind + b*KIND_LEN, q, i2h);
      const float2* ep = (q==0)? user_emb : (q==1)? age_emb : (q==2)? gen_emb : occ_emb;
      int ei = (q==0)? userid[b] : (q==1)? age[b] : (q==2)? gen[b] : occ[b];
      #pragma unroll
      for(int k=0;k<4;k++) exr[k] = ep[ei*4+k];
    }
    // MFMA1: hidden[64x64] = [X1|X2]·HW1 + ab1, relu -> H1 (f16)
    {
      uint4 a1[6];
      #pragma unroll
      for(int t=0;t<3;t++) a1[t]   = lsu4[X1B + sr*13 + 4*t + kb];
      #pragma unroll
      for(int t=0;t<3;t++) a1[3+t] = lsu4[X2B + sr*13 + 4*t + kb];
      _Float16* h1p = (_Float16*)(ls4 + H1B);
      #pragma unroll
      for(int n=0;n<4;n++){
        float bb = hb1[n];
        v4f c = {bb,bb,bb,bb};
        #pragma unroll
        for(int t=0;t<6;t++){
          uint4 bw = wsu4[(n*6+t)*64 + l];
          c = __builtin_amdgcn_mfma_f32_16x16x32_f16(C8H(a1[t]), C8H(bw), c, 0, 0, 0);
        }
        #pragma unroll
        for(int i=0;i<4;i++)
          h1p[(16*wv + 4*kb + i)*72 + 16*n + (l&15)] = (_Float16)fmaxf(c[i],0.f);
      }
    }
    __syncthreads();                       // BAR2: H1 ready
    // MFMA2 (in-register): h2 rows 4kb+i, cols 16n2+(l&15)
    v4f c20, c21;
    {
      uint4 a2[2];
      #pragma unroll
      for(int t=0;t<2;t++) a2[t] = lsu4[H1B + sr*9 + 4*t + kb];
      c20 = (v4f){hb2[0],hb2[0],hb2[0],hb2[0]};
      c21 = (v4f){hb2[1],hb2[1],hb2[1],hb2[1]};
      #pragma unroll
      for(int t=0;t<2;t++){
        uint4 bw0 = wsu4[AW2F4 + t*64 + l];
        uint4 bw1 = wsu4[AW2F4 + (2+t)*64 + l];
        c20 = __builtin_amdgcn_mfma_f32_16x16x32_f16(C8H(a2[t]), C8H(bw0), c20, 0, 0, 0);
        c21 = __builtin_amdgcn_mfma_f32_16x16x32_f16(C8H(a2[t]), C8H(bw1), c21, 0, 0, 0);
      }
    }
    // act tail in-register: p[i] = w3·relu(h2[row 4kb+i]); 16-lane reduce
    {
      float p0 = w3a*fmaxf(c20[0],0.f) + w3b*fmaxf(c21[0],0.f);
      float p1 = w3a*fmaxf(c20[1],0.f) + w3b*fmaxf(c21[1],0.f);
      float p2 = w3a*fmaxf(c20[2],0.f) + w3b*fmaxf(c21[2],0.f);
      float p3 = w3a*fmaxf(c20[3],0.f) + w3b*fmaxf(c21[3],0.f);
      p0 = rsum16(p0); p1 = rsum16(p1); p2 = rsum16(p2); p3 = rsum16(p3);
      float scp = (ii==0)? p0 : (ii==1)? p1 : (ii==2)? p2 : p3;
      float sc = scp + ab3v;
      #pragma unroll
      for(int j=0;j<11;j++){
        float sx = (float)i1c[j].x, sy = (float)i1c[j].y;
        poolv[j] = __builtin_elementwise_fma(mk2(sx*sc, sy*sc), mk2(sx, sy), poolv[j]);
      }
    }
    #pragma unroll
    for(int j=0;j<11;j++) i1c[j] = i1n[j];
  }

  // ---- MLP phase ----
  v2h fe[26];
  #pragma unroll
  for(int k=0;k<4;k++) fe[k] = pkh(exr[k].x, exr[k].y);
  #pragma unroll
  for(int j=0;j<11;j++) fe[4+j]  = i2h[j];
  #pragma unroll
  for(int j=0;j<11;j++) fe[15+j] = pkh(poolv[j].x, poolv[j].y);

  __syncthreads();   // BAR-M0: all waves done with hist regions

  // X-MLP write: [64][29 f4], k-order [q][56]
  {
    unsigned xd[28];
    #pragma unroll
    for(int u=0;u<26;u++) xd[u] = __builtin_bit_cast(unsigned, fe[u]);
    xd[26] = 0; xd[27] = 0;
    uint4* xp = (uint4*)(ls4 + wid*29 + q*7);
    #pragma unroll
    for(int ct=0; ct<7; ct++){
      uint4 t; t.x=xd[4*ct]; t.y=xd[4*ct+1]; t.z=xd[4*ct+2]; t.w=xd[4*ct+3];
      xp[ct] = t;
    }
  }
  __syncthreads();   // BAR-M1: X-MLP complete
  uint4 af[7];
  #pragma unroll
  for(int t=0;t<7;t++) af[t] = lsu4[sr*29 + t*4 + kb];
  __syncthreads();   // BAR-M2: A-frags loaded; [0,1856) reusable

  // stage tail M3H weights into freed region [1664,1926); drained by BAR-M3
  ldst16(ls4 + M3HL + (tid>>6)*66 + (tid&63), ws4 + M3H4 + tid);

  // MLP1: H1[64x128] = X·W1 + mb1, ReLU
  v4f acc1[8];
  #pragma unroll
  for(int n=0;n<8;n++){
    float bb = ls[MB1F + n*16 + (l&15)];
    v4f c = {bb, bb, bb, bb};
    #pragma unroll
    for(int t=0;t<7;t++){
      uint4 bw = wsu4[MW1F4 + (n*7+t)*64 + l];
      c = __builtin_amdgcn_mfma_f32_16x16x32_f16(C8H(af[t]), C8H(bw), c, 0, 0, 0);
    }
    acc1[n] = c;
  }
  {
    _Float16* h1p = (_Float16*)ls;   // row stride 136 f16 (17 f4)
    #pragma unroll
    for(int n=0;n<8;n++)
      #pragma unroll
      for(int i=0;i<4;i++)
        h1p[(16*wv + 4*kb + i)*136 + 16*n + (l&15)] =
            (_Float16)fmaxf(acc1[n][i], 0.f);
  }
  __syncthreads();   // BAR-M3: H1-MLP ready (also drains M3H staging)

  // MLP2: H2[64x64] = H1·W2 + mb2, ReLU
  v4f acc2[4];
  #pragma unroll
  for(int n2=0;n2<4;n2++){
    float bb = ls[LMB2 + n2*16 + (l&15)];
    v4f c = {bb, bb, bb, bb};
    acc2[n2] = c;
  }
  #pragma unroll
  for(int t2=0;t2<4;t2++){
    uint4 aw = lsu4[sr*17 + t2*4 + kb];
    #pragma unroll
    for(int n2=0;n2<4;n2++){
      uint4 bw = wsu4[MW2F4 + (n2*4+t2)*64 + l];
      acc2[n2] = __builtin_amdgcn_mfma_f32_16x16x32_f16(C8H(aw), C8H(bw), acc2[n2], 0, 0, 0);
    }
  }
  {
    _Float16* h2p = (_Float16*)(ls4 + 1088);   // row stride 72 f16 (9 f4)
    #pragma unroll
    for(int n2=0;n2<4;n2++)
      #pragma unroll
      for(int i=0;i<4;i++)
        h2p[(16*wv + 4*kb + i)*72 + 16*n2 + (l&15)] =
            (_Float16)fmaxf(acc2[n2][i], 0.f);
  }
  __syncthreads();   // BAR-M4: H2-MLP + M3H ready

  // tail: layers 3+4 (per-sample quad, i-paired fdot2)
  v2h hp3[8];
  {
    const uint4* hr = (const uint4*)(ls4 + 1088 + wid*9 + 2*q);
    uint4 d0 = hr[0], d1 = hr[1];
    hp3[0]=C2H(d0.x); hp3[1]=C2H(d0.y); hp3[2]=C2H(d0.z); hp3[3]=C2H(d0.w);
    hp3[4]=C2H(d1.x); hp3[5]=C2H(d1.y); hp3[6]=C2H(d1.z); hp3[7]=C2H(d1.w);
  }
  float x = ls[LMB4];
  #pragma unroll
  for(int g=0;g<4;g++){
    float a[8];
    #pragma unroll
    for(int j=0;j<8;j++) a[j]=0.f;
    #pragma unroll
    for(int ip=0;ip<8;ip++){
      const uint4* w3p = (const uint4*)(ls4 + M3HL + q*66 + ip*8 + 2*g);
      uint4 b0=w3p[0], b1=w3p[1];
      a[0]=FD2(C2H(b0.x),hp3[ip],a[0]); a[1]=FD2(C2H(b0.y),hp3[ip],a[1]);
      a[2]=FD2(C2H(b0.z),hp3[ip],a[2]); a[3]=FD2(C2H(b0.w),hp3[ip],a[3]);
      a[4]=FD2(C2H(b1.x),hp3[ip],a[4]); a[5]=FD2(C2H(b1.y),hp3[ip],a[5]);
      a[6]=FD2(C2H(b1.z),hp3[ip],a[6]); a[7]=FD2(C2H(b1.w),hp3[ip],a[7]);
    }
    #pragma unroll
    for(int j=0;j<8;j++) a[j] = bsum4(a[j]);
    #pragma unroll
    for(int j=0;j<8;j++)
      x += ls[LM4+8*g+j] * fmaxf(a[j] + ls[LMB3+8*g+j], 0.f);
  }

  if(q==0) out[b] = 1.0f/(1.0f + __expf(-x));
}

extern "C" void kernel_launch(void* const* d_in, const int* in_sizes, int n_in,
                              void* d_out, int out_size, void* d_ws, size_t ws_size,
                              hipStream_t stream){
  const int* userid    = (const int*)d_in[0];
  const int* itemid    = (const int*)d_in[1];
  const int* age       = (const int*)d_in[2];
  const int* gen       = (const int*)d_in[3];
  const int* occ       = (const int*)d_in[4];
  const int* item_kind = (const int*)d_in[5];
  const int* his_id    = (const int*)d_in[6];
  const int* his_kind  = (const int*)d_in[7];
  const float2* user_emb = (const float2*)d_in[8];
  const float2* item_emb = (const float2*)d_in[9];
  const float2* age_emb  = (const float2*)d_in[10];
  const float2* gen_emb  = (const float2*)d_in[11];
  const float2* occ_emb  = (const float2*)d_in[12];
  const float2* kind_emb = (const float2*)d_in[13];
  float* ws = (float*)d_ws;

  din_prep<<<(PREP_N+255)/256, 256, 0, stream>>>(
      (fp)d_in[14], (fp)d_in[15], (fp)d_in[16], (fp)d_in[17], (fp)d_in[18], (fp)d_in[19],
      (fp)d_in[20], (fp)d_in[21], (fp)d_in[22], (fp)d_in[23], (fp)d_in[24], (fp)d_in[25],
      (fp)d_in[26], (fp)d_in[27], ws);

  din_main<<<BATCH/SB, NTH, 0, stream>>>(
      userid, itemid, age, gen, occ, item_kind, his_id, his_kind,
      user_emb, item_emb, age_emb, gen_emb, occ_emb, kind_emb,
      ws, (float*)d_out);
}

// Round 17
// 275.498 us; speedup vs baseline: 1.0036x; 1.0036x over previous
//
#include <hip/hip_runtime.h>
#include <cstdint>
#include <math.h>

#define BATCH    65536
#define HIS_LEN  5
#define KIND_LEN 10
#define SB       64    // samples per block
#define NTH      256   // threads per block (4 waves); 4 threads per sample

typedef float    v2f __attribute__((ext_vector_type(2)));
typedef float    v4f __attribute__((ext_vector_type(4)));
typedef _Float16 v2h __attribute__((ext_vector_type(2)));
typedef _Float16 v8h __attribute__((ext_vector_type(8)));
__device__ __forceinline__ v2f mk2(float a, float b){ v2f r; r.x=a; r.y=b; return r; }
#define C2H(u)  __builtin_bit_cast(v2h,(unsigned)(u))
#define C8H(u4) __builtin_bit_cast(v8h,(u4))

#if __has_builtin(__builtin_amdgcn_fdot2)
__device__ __forceinline__ float FD2(v2h a, v2h b, float c){
  return __builtin_amdgcn_fdot2(a, b, c, false);
}
#else
__device__ __forceinline__ float FD2(v2h a, v2h b, float c){
  return c + (float)a.x*(float)b.x + (float)a.y*(float)b.y;
}
#endif

__device__ __forceinline__ unsigned short f2h(float f){
  return __builtin_bit_cast(unsigned short, (_Float16)f);
}
__device__ __forceinline__ unsigned pack2h(float a, float b){
  return (unsigned)f2h(a) | ((unsigned)f2h(b) << 16);
}
__device__ __forceinline__ v2h pkh(float a, float b){
  return __builtin_bit_cast(v2h, __builtin_amdgcn_cvt_pkrtz(a, b));
}

// ---- ws layout (dword offsets) ----
#define OFF_HW1F 0      // 6144: hist W1 B-frags [4n][6t][64 lane][4dw], K=192=[i1|i2]
#define OFF_AW2F 6144   // 1024: act W2 B-frags [2n2][2t2][64][4]
#define OFF_PF   7168   // 258: AB1 64|AB2 32|W3 32|AB3 1|MB2 64|MB3 32|M4 32|MB4 1
#define OFF_M3H  7428   // 1024: tail M3 f16 pairs [4q][8ip][32dw]
#define OFF_MW1F 8452   // 14336: MLP W1 B-frags [8n][7t][64][4]
#define OFF_MB1  22788  // 128
#define OFF_MW2F 22916  // 4096: MLP W2 B-frags [4n2][4t2][64][4]
#define PREP_N   27012
// f4 indices into ws
#define AW2F4 1536
#define M3H4  1857
#define MW1F4 2113
#define MW2F4 5729

// ---- LDS layout (f4 units unless noted) ----
// All X/H regions are row-partitioned by wave: wave wv owns rows
// [16wv,16wv+16). H1/H2 producer->consumer pairs are wave-local (same-wave
// DS ops are in-order) -> no barrier; X1 keeps one per-step barrier as a
// scheduling anchor (R14 lesson: zero anchors explodes live ranges).
#define X2B   0        // i2 features [64][13 f4]
#define X1B   832      // i1 features per step [64][13 f4]
#define H1B   1664     // hist hidden f16 [64][9 f4]
#define H2B   2240     // act hidden f32 [64][9 f4]
#define M3HL  2816     // tail weights (skewed, q*66), 262 f4
#define LAB1  12312
#define LAB2  12376
#define LW3   12408
#define LAB3  12440
#define LMB2  12441
#define LMB3  12505
#define LM4   12537
#define LMB4  12569
#define MB1F  12572
#define LDSF  12700
// MLP phase reuses f4 [0,1856): X-MLP [64][29]; then H1-MLP [0,1088) s17,
// H2-MLP [1088,1664) s9

typedef const float* fp;

__device__ __forceinline__ float m1s_val(fp m1, int o, int q, int t){
  if(t >= 52) return 0.f;
  int src;
  if(t<8){ int E = (q==0)?0:(8+8*q); src = E + t; }
  else if(t<30){ int d=t-8; int idx = 8*(d>>1)+2*q+(d&1);
                 src = (idx<8) ? (8+idx) : (32+idx); }
  else { int d=t-30; int idx = 8*(d>>1)+2*q+(d&1); src = 120+idx; }
  return m1[o*208 + src];
}
__device__ __forceinline__ float m1k(fp m1, int o, int k){
  return m1s_val(m1, o, k/56, k%56);
}
__device__ __forceinline__ float w1c_val(fp aw1, int o, int q, int h, int d){
  if(d >= 22) return 0.f;
  int idx = 8*(d>>1) + 2*q + (d&1);
  return h ? (aw1[o*264+176+idx] - aw1[o*264+88+idx])
           : (aw1[o*264+idx]     + aw1[o*264+88+idx]);
}
__device__ __forceinline__ float hw1v(fp aw1, int o, int k){
  int h = (k >= 96) ? 1 : 0;
  int kk = k - 96*h;
  int q = kk/24, d = kk%24;
  return (d<22) ? w1c_val(aw1,o,q,h,d) : 0.f;
}

__global__ void din_prep(fp aw1, fp ab1, fp aw2, fp ab2, fp aw3, fp ab3,
                         fp m1,  fp mb1, fp m2,  fp mb2, fp m3,  fp mb3,
                         fp m4,  fp mb4, float* __restrict__ ws){
  int j = blockIdx.x*blockDim.x + threadIdx.x;
  unsigned* wsu = (unsigned*)ws;
  if(j < 6144){ // HW1F: [4n][6t][64][4]
    int frag = j>>2, jr = j&3;
    int lane = frag & 63, nt = frag >> 6;
    int n = nt/6, t = nt%6;
    int o = 16*n + (lane&15);
    int k0 = t*32 + ((lane>>4)<<3) + 2*jr;
    wsu[OFF_HW1F + j] = pack2h(hw1v(aw1,o,k0), hw1v(aw1,o,k0+1));
    return;
  } j -= 6144;
  if(j < 1024){ // AW2F: [2n2][2t2][64][4]
    int frag = j>>2, jr = j&3;
    int lane = frag & 63, nt = frag >> 6;
    int n2 = nt>>1, t2 = nt&1;
    int o = 16*n2 + (lane&15);
    int k0 = t2*32 + ((lane>>4)<<3) + 2*jr;
    wsu[OFF_AW2F + j] = pack2h(aw2[o*64 + k0], aw2[o*64 + k0+1]);
    return;
  } j -= 1024;
  if(j < 258){ // PF
    float v;
    if(j < 64)       v = ab1[j];
    else if(j < 96)  v = ab2[j-64];
    else if(j < 128) v = aw3[j-96];
    else if(j < 129) v = ab3[0];
    else if(j < 193) v = mb2[j-129];
    else if(j < 225) v = mb3[j-193];
    else if(j < 257) v = m4[j-225];
    else             v = mb4[0];
    ws[OFF_PF + j] = v; return;
  } j -= 258;
  if(j < 2){ ws[OFF_PF+258+j] = 0.f; return; } j -= 2;
  if(j < 1024){ // M3H
    int qq = j>>8, rr = j&255, ip = rr>>5, dw = rr&31;
    wsu[OFF_M3H + j] = pack2h(m3[dw*64 + 16*qq + 2*ip], m3[dw*64 + 16*qq + 2*ip+1]);
    return;
  } j -= 1024;
  if(j < 14336){ // MW1F
    int frag = j>>2, jr = j&3;
    int lane = frag & 63, nt = frag >> 6;
    int n = nt/7, t = nt - 7*n;
    int o = 16*n + (lane&15);
    int k0 = t*32 + ((lane>>4)<<3) + 2*jr;
    wsu[OFF_MW1F + j] = pack2h(m1k(m1,o,k0), m1k(m1,o,k0+1));
    return;
  } j -= 14336;
  if(j < 128){ ws[OFF_MB1 + j] = mb1[j]; return; } j -= 128;
  if(j < 4096){ // MW2F
    int frag = j>>2, jr = j&3;
    int lane = frag & 63, nt = frag >> 6;
    int n2 = nt>>2, t2 = nt&3;
    int o = 16*n2 + (lane&15);
    int k0 = t2*32 + ((lane>>4)<<3) + 2*jr;
    wsu[OFF_MW2F + j] = pack2h(m2[o*128 + k0], m2[o*128 + k0+1]);
    return;
  }
}

// DPP quad reduction
template<int CTL>
__device__ __forceinline__ float qp(float v){
  return __uint_as_float((unsigned)__builtin_amdgcn_update_dpp(
      0, (int)__float_as_uint(v), CTL, 0xF, 0xF, true));
}
__device__ __forceinline__ float bsum4(float v){
  v += qp<0xB1>(v);
  v += qp<0x4E>(v);
  return v;
}

__device__ __forceinline__ void ldst16(void* l, const void* g){
  __builtin_amdgcn_global_load_lds(
      (const __attribute__((address_space(1))) unsigned int*)(uintptr_t)g,
      (__attribute__((address_space(3))) unsigned int*)(uintptr_t)l, 16, 0, 0);
}
__device__ __forceinline__ void ldst4(void* l, const void* g){
  __builtin_amdgcn_global_load_lds(
      (const __attribute__((address_space(1))) unsigned int*)(uintptr_t)g,
      (__attribute__((address_space(3))) unsigned int*)(uintptr_t)l, 4, 0, 0);
}

__device__ __forceinline__ void gather_h(const float2* __restrict__ itemp,
                                         const float2* __restrict__ kindp,
                                         int item_idx, const int* __restrict__ kidx,
                                         int q, v2h* f){
  float2 v = itemp[item_idx*4 + q];
  f[0] = pkh(v.x, v.y);
  #pragma unroll
  for(int r=0;r<KIND_LEN;r++){
    int ki = kidx[r];
    float2 w = kindp[ki*4 + q];
    float mx = ki ? w.x : 0.f, my = ki ? w.y : 0.f;
    f[1+r] = pkh(mx, my);
  }
}

__device__ __forceinline__ void write_X(float4* ls4, int base, int wid, int q,
                                        const v2h* f){
  unsigned xd[12];
  #pragma unroll
  for(int r=0;r<11;r++) xd[r] = __builtin_bit_cast(unsigned, f[r]);
  xd[11] = 0;
  uint4* xp = (uint4*)(ls4 + base + wid*13 + 3*q);
  #pragma unroll
  for(int c=0;c<3;c++){
    uint4 t; t.x=xd[4*c]; t.y=xd[4*c+1]; t.z=xd[4*c+2]; t.w=xd[4*c+3];
    xp[c] = t;
  }
}

// 256 threads; 64 samples/block; history+MLP via MFMA (R11 structure).
// History: 1 barrier/step (X1 anchor); H1/H2 handoffs are wave-local.
__global__ void __launch_bounds__(NTH, 3)
din_main(const int* __restrict__ userid, const int* __restrict__ itemid,
         const int* __restrict__ age,    const int* __restrict__ gen,
         const int* __restrict__ occ,    const int* __restrict__ item_kind,
         const int* __restrict__ his_id, const int* __restrict__ his_kind,
         const float2* __restrict__ user_emb, const float2* __restrict__ item_emb,
         const float2* __restrict__ age_emb,  const float2* __restrict__ gen_emb,
         const float2* __restrict__ occ_emb,  const float2* __restrict__ kind_emb,
         const float* __restrict__ ws, float* __restrict__ out){
  const int tid  = threadIdx.x;
  const int q    = tid & 3;
  const int sl   = (tid & 63) >> 2;
  const int wv   = __builtin_amdgcn_readfirstlane(tid >> 6);
  const int wid  = wv*16 + sl;                 // sample-in-block 0..63
  const int b    = blockIdx.x*SB + wid;
  const int l    = tid & 63;
  const int sr   = wv*16 + (l&15);             // MFMA A-row (sample)
  const int kb   = l >> 4;                     // MFMA K-chunk 0..3

  __shared__ __align__(16) float ls[LDSF];
  float4* ls4 = (float4*)ls;
  const uint4* lsu4 = (const uint4*)ls;
  const float* wsc = ws;
  const float4* ws4 = (const float4*)ws;
  const uint4* wsu4 = (const uint4*)ws;

  // ---- initial async staging: PF(258) + MB1(128) + M3H(skewed) ----
  ldst4(ls + LAB1 + tid, wsc + OFF_PF + tid);
  if(tid < 2)   ldst4(ls + LAB1 + 256 + tid, wsc + OFF_PF + 256 + tid);
  if(tid < 128) ldst4(ls + MB1F + tid, wsc + OFF_MB1 + tid);
  ldst16(ls4 + M3HL + (tid>>6)*66 + (tid&63), ws4 + M3H4 + tid);

  // ---- gather i2 -> X2 (persistent K-tiles 3..5) ----
  {
    v2h i2t[11];
    gather_h(item_emb, kind_emb, itemid[b], item_kind + b*KIND_LEN, q, i2t);
    write_X(ls4, X2B, wid, q, i2t);
  }
  // ---- gather step-0 i1 ----
  v2h i1c[11], i1n[11];
  gather_h(item_emb, kind_emb, his_id[b*HIS_LEN], his_kind + b*HIS_LEN*KIND_LEN,
           q, i1c);

  v2f poolv[11];
  #pragma unroll
  for(int d=0;d<11;d++) poolv[d]=mk2(0.f,0.f);
  v2h i2h[11];
  float2 exr[4];

  __syncthreads();   // BAR-0: staging + X2 drained

  // ---- hoisted loop-invariants ----
  float hb1[4], hb2[2], w3r[8];
  #pragma unroll
  for(int n=0;n<4;n++)  hb1[n] = ls[LAB1 + 16*n + (l&15)];
  #pragma unroll
  for(int n2=0;n2<2;n2++) hb2[n2] = ls[LAB2 + 16*n2 + (l&15)];
  #pragma unroll
  for(int k=0;k<8;k++)  w3r[k] = ls[LW3 + 8*q + k];
  const float ab3v = ls[LAB3];
  uint4 awf[4];
  #pragma unroll
  for(int t=0;t<4;t++) awf[t] = wsu4[AW2F4 + t*64 + l];   // act-W2 B-frags

  // ---- history: 5 steps, MFMA act-unit, 1 barrier/step ----
  #pragma unroll 1
  for(int s=0;s<5;s++){
    write_X(ls4, X1B, wid, q, i1c);
    __syncthreads();                       // BAR1: X1 ready (per-step anchor)
    if(s < 4){
      gather_h(item_emb, kind_emb, his_id[b*HIS_LEN+s+1],
               his_kind + (b*HIS_LEN+s+1)*KIND_LEN, q, i1n);
    } else {
      gather_h(item_emb, kind_emb, itemid[b], item_kind + b*KIND_LEN, q, i2h);
      const float2* ep = (q==0)? user_emb : (q==1)? age_emb : (q==2)? gen_emb : occ_emb;
      int ei = (q==0)? userid[b] : (q==1)? age[b] : (q==2)? gen[b] : occ[b];
      #pragma unroll
      for(int k=0;k<4;k++) exr[k] = ep[ei*4+k];
    }
    // MFMA1: hidden[64x64] = [X1|X2]·HW1 + ab1, relu -> H1 (f16)
    {
      uint4 a1[6];
      #pragma unroll
      for(int t=0;t<3;t++) a1[t]   = lsu4[X1B + sr*13 + 4*t + kb];
      #pragma unroll
      for(int t=0;t<3;t++) a1[3+t] = lsu4[X2B + sr*13 + 4*t + kb];
      _Float16* h1p = (_Float16*)(ls4 + H1B);
      #pragma unroll
      for(int n=0;n<4;n++){
        float bb = hb1[n];
        v4f c = {bb,bb,bb,bb};
        #pragma unroll
        for(int t=0;t<6;t++){
          uint4 bw = wsu4[(n*6+t)*64 + l];
          c = __builtin_amdgcn_mfma_f32_16x16x32_f16(C8H(a1[t]), C8H(bw), c, 0, 0, 0);
        }
        #pragma unroll
        for(int i=0;i<4;i++)
          h1p[(16*wv + 4*kb + i)*72 + 16*n + (l&15)] = (_Float16)fmaxf(c[i],0.f);
      }
    }
    // (no barrier: H1 rows [16wv,16wv+16) produced and consumed by this wave;
    //  same-wave DS ops are in-order and overlap forces compiler ordering)
    // MFMA2: h2[64x32] = H1·AW2 + ab2, relu -> H2 (f32)
    {
      uint4 a2[2];
      #pragma unroll
      for(int t=0;t<2;t++) a2[t] = lsu4[H1B + sr*9 + 4*t + kb];
      float* h2p = (float*)(ls4 + H2B);
      #pragma unroll
      for(int n2=0;n2<2;n2++){
        float bb = hb2[n2];
        v4f c = {bb,bb,bb,bb};
        #pragma unroll
        for(int t=0;t<2;t++){
          uint4 bw = awf[n2*2+t];
          c = __builtin_amdgcn_mfma_f32_16x16x32_f16(C8H(a2[t]), C8H(bw), c, 0, 0, 0);
        }
        #pragma unroll
        for(int i=0;i<4;i++)
          h2p[(16*wv + 4*kb + i)*36 + 16*n2 + (l&15)] = fmaxf(c[i],0.f);
      }
    }
    // (no barrier: H2 handoff also wave-local)
    // act tail: sc = w3·H2 + ab3 ; pool += sc * i1^2
    {
      const float4* hr = (const float4*)(ls4 + H2B + wid*9 + 2*q);
      float4 h0 = hr[0], h1v = hr[1];
      float scp = h0.x*w3r[0] + h0.y*w3r[1] + h0.z*w3r[2] + h0.w*w3r[3]
                + h1v.x*w3r[4] + h1v.y*w3r[5] + h1v.z*w3r[6] + h1v.w*w3r[7];
      float sc = bsum4(scp) + ab3v;
      #pragma unroll
      for(int j=0;j<11;j++){
        float sx = (float)i1c[j].x, sy = (float)i1c[j].y;
        poolv[j] = __builtin_elementwise_fma(mk2(sx*sc, sy*sc), mk2(sx, sy), poolv[j]);
      }
    }
    #pragma unroll
    for(int j=0;j<11;j++) i1c[j] = i1n[j];
  }

  // ---- MLP phase ----
  v2h fe[26];
  #pragma unroll
  for(int k=0;k<4;k++) fe[k] = pkh(exr[k].x, exr[k].y);
  #pragma unroll
  for(int j=0;j<11;j++) fe[4+j]  = i2h[j];
  #pragma unroll
  for(int j=0;j<11;j++) fe[15+j] = pkh(poolv[j].x, poolv[j].y);

  __syncthreads();   // BAR-M0: all waves done with hist regions

  // X-MLP write: [64][29 f4], k-order [q][56]
  {
    unsigned xd[28];
    #pragma unroll
    for(int u=0;u<26;u++) xd[u] = __builtin_bit_cast(unsigned, fe[u]);
    xd[26] = 0; xd[27] = 0;
    uint4* xp = (uint4*)(ls4 + wid*29 + q*7);
    #pragma unroll
    for(int ct=0; ct<7; ct++){
      uint4 t; t.x=xd[4*ct]; t.y=xd[4*ct+1]; t.z=xd[4*ct+2]; t.w=xd[4*ct+3];
      xp[ct] = t;
    }
  }
  __syncthreads();   // BAR-M1: X-MLP complete
  uint4 af[7];
  #pragma unroll
  for(int t=0;t<7;t++) af[t] = lsu4[sr*29 + t*4 + kb];
  __syncthreads();   // BAR-M2: A-frags loaded; [0,1856) reusable

  // MLP1: H1[64x128] = X·W1 + mb1, ReLU
  v4f acc1[8];
  #pragma unroll
  for(int n=0;n<8;n++){
    float bb = ls[MB1F + n*16 + (l&15)];
    v4f c = {bb, bb, bb, bb};
    #pragma unroll
    for(int t=0;t<7;t++){
      uint4 bw = wsu4[MW1F4 + (n*7+t)*64 + l];
      c = __builtin_amdgcn_mfma_f32_16x16x32_f16(C8H(af[t]), C8H(bw), c, 0, 0, 0);
    }
    acc1[n] = c;
  }
  {
    _Float16* h1p = (_Float16*)ls;   // row stride 136 f16 (17 f4)
    #pragma unroll
    for(int n=0;n<8;n++)
      #pragma unroll
      for(int i=0;i<4;i++)
        h1p[(16*wv + 4*kb + i)*136 + 16*n + (l&15)] =
            (_Float16)fmaxf(acc1[n][i], 0.f);
  }
  __syncthreads();   // BAR-M3: H1-MLP ready

  // MLP2: H2[64x64] = H1·W2 + mb2, ReLU
  v4f acc2[4];
  #pragma unroll
  for(int n2=0;n2<4;n2++){
    float bb = ls[LMB2 + n2*16 + (l&15)];
    v4f c = {bb, bb, bb, bb};
    acc2[n2] = c;
  }
  #pragma unroll
  for(int t2=0;t2<4;t2++){
    uint4 aw = lsu4[sr*17 + t2*4 + kb];
    #pragma unroll
    for(int n2=0;n2<4;n2++){
      uint4 bw = wsu4[MW2F4 + (n2*4+t2)*64 + l];
      acc2[n2] = __builtin_amdgcn_mfma_f32_16x16x32_f16(C8H(aw), C8H(bw), acc2[n2], 0, 0, 0);
    }
  }
  {
    _Float16* h2p = (_Float16*)(ls4 + 1088);   // row stride 72 f16 (9 f4)
    #pragma unroll
    for(int n2=0;n2<4;n2++)
      #pragma unroll
      for(int i=0;i<4;i++)
        h2p[(16*wv + 4*kb + i)*72 + 16*n2 + (l&15)] =
            (_Float16)fmaxf(acc2[n2][i], 0.f);
  }
  __syncthreads();   // BAR-M4: H2-MLP ready

  // tail: layers 3+4 (per-sample quad, i-paired fdot2)
  v2h hp3[8];
  {
    const uint4* hr = (const uint4*)(ls4 + 1088 + wid*9 + 2*q);
    uint4 d0 = hr[0], d1 = hr[1];
    hp3[0]=C2H(d0.x); hp3[1]=C2H(d0.y); hp3[2]=C2H(d0.z); hp3[3]=C2H(d0.w);
    hp3[4]=C2H(d1.x); hp3[5]=C2H(d1.y); hp3[6]=C2H(d1.z); hp3[7]=C2H(d1.w);
  }
  float x = ls[LMB4];
  #pragma unroll
  for(int g=0;g<4;g++){
    float a[8];
    #pragma unroll
    for(int j=0;j<8;j++) a[j]=0.f;
    #pragma unroll
    for(int ip=0;ip<8;ip++){
      const uint4* w3p = (const uint4*)(ls4 + M3HL + q*66 + ip*8 + 2*g);
      uint4 b0=w3p[0], b1=w3p[1];
      a[0]=FD2(C2H(b0.x),hp3[ip],a[0]); a[1]=FD2(C2H(b0.y),hp3[ip],a[1]);
      a[2]=FD2(C2H(b0.z),hp3[ip],a[2]); a[3]=FD2(C2H(b0.w),hp3[ip],a[3]);
      a[4]=FD2(C2H(b1.x),hp3[ip],a[4]); a[5]=FD2(C2H(b1.y),hp3[ip],a[5]);
      a[6]=FD2(C2H(b1.z),hp3[ip],a[6]); a[7]=FD2(C2H(b1.w),hp3[ip],a[7]);
    }
    #pragma unroll
    for(int j=0;j<8;j++) a[j] = bsum4(a[j]);
    #pragma unroll
    for(int j=0;j<8;j++)
      x += ls[LM4+8*g+j] * fmaxf(a[j] + ls[LMB3+8*g+j], 0.f);
  }

  if(q==0) out[b] = 1.0f/(1.0f + __expf(-x));
}

extern "C" void kernel_launch(void* const* d_in, const int* in_sizes, int n_in,
                              void* d_out, int out_size, void* d_ws, size_t ws_size,
                              hipStream_t stream){
  const int* userid    = (const int*)d_in[0];
  const int* itemid    = (const int*)d_in[1];
  const int* age       = (const int*)d_in[2];
  const int* gen       = (const int*)d_in[3];
  const int* occ       = (const int*)d_in[4];
  const int* item_kind = (const int*)d_in[5];
  const int* his_id    = (const int*)d_in[6];
  const int* his_kind  = (const int*)d_in[7];
  const float2* user_emb = (const float2*)d_in[8];
  const float2* item_emb = (const float2*)d_in[9];
  const float2* age_emb  = (const float2*)d_in[10];
  const float2* gen_emb  = (const float2*)d_in[11];
  const float2* occ_emb  = (const float2*)d_in[12];
  const float2* kind_emb = (const float2*)d_in[13];
  float* ws = (float*)d_ws;

  din_prep<<<(PREP_N+255)/256, 256, 0, stream>>>(
      (fp)d_in[14], (fp)d_in[15], (fp)d_in[16], (fp)d_in[17], (fp)d_in[18], (fp)d_in[19],
      (fp)d_in[20], (fp)d_in[21], (fp)d_in[22], (fp)d_in[23], (fp)d_in[24], (fp)d_in[25],
      (fp)d_in[26], (fp)d_in[27], ws);

  din_main<<<BATCH/SB, NTH, 0, stream>>>(
      userid, itemid, age, gen, occ, item_kind, his_id, his_kind,
      user_emb, item_emb, age_emb, gen_emb, occ_emb, kind_emb,
      ws, (float*)d_out);
}

// Round 18
// 236.750 us; speedup vs baseline: 1.1679x; 1.1637x over previous
//
#include <hip/hip_runtime.h>
#include <cstdint>
#include <math.h>

#define BATCH    65536
#define HIS_LEN  5
#define KIND_LEN 10
#define SB       64    // samples per block
#define NTH      256   // threads per block (4 waves); 4 threads per sample

typedef float    v2f __attribute__((ext_vector_type(2)));
typedef float    v4f __attribute__((ext_vector_type(4)));
typedef _Float16 v2h __attribute__((ext_vector_type(2)));
typedef _Float16 v8h __attribute__((ext_vector_type(8)));
__device__ __forceinline__ v2f mk2(float a, float b){ v2f r; r.x=a; r.y=b; return r; }
#define C2H(u)  __builtin_bit_cast(v2h,(unsigned)(u))
#define C8H(u4) __builtin_bit_cast(v8h,(u4))

#if __has_builtin(__builtin_amdgcn_fdot2)
__device__ __forceinline__ float FD2(v2h a, v2h b, float c){
  return __builtin_amdgcn_fdot2(a, b, c, false);
}
#else
__device__ __forceinline__ float FD2(v2h a, v2h b, float c){
  return c + (float)a.x*(float)b.x + (float)a.y*(float)b.y;
}
#endif

__device__ __forceinline__ unsigned short f2h(float f){
  return __builtin_bit_cast(unsigned short, (_Float16)f);
}
__device__ __forceinline__ unsigned pack2h(float a, float b){
  return (unsigned)f2h(a) | ((unsigned)f2h(b) << 16);
}
__device__ __forceinline__ v2h pkh(float a, float b){
  return __builtin_bit_cast(v2h, __builtin_amdgcn_cvt_pkrtz(a, b));
}

// ---- ws layout (dword offsets) ----
#define OFF_HW1F 0      // 6144: hist W1 B-frags [4n][6t][64 lane][4dw], K=192=[i1|i2]
#define OFF_AW2F 6144   // 1024: act W2 B-frags [2n2][2t2][64][4]
#define OFF_PF   7168   // 258: AB1 64|AB2 32|W3 32|AB3 1|MB2 64|MB3 32|M4 32|MB4 1
#define OFF_M3H  7428   // 1024: tail M3 f16 pairs [4q][8ip][32dw]
#define OFF_MW1F 8452   // 14336: MLP W1 B-frags [8n][7t][64][4]
#define OFF_MB1  22788  // 128
#define OFF_MW2F 22916  // 4096: MLP W2 B-frags [4n2][4t2][64][4]
#define PREP_N   27012
// f4 indices into ws
#define AW2F4 1536
#define M3H4  1857
#define MW1F4 2113
#define MW2F4 5729

// ---- LDS layout (f4 units unless noted) ----
#define X2B   0        // i2 features [64][13 f4]
#define X1B   832      // i1 features per step [64][13 f4]
#define H1B   1664     // hist hidden f16 [64][9 f4]
#define H2B   2240     // act hidden f32 [64][9 f4]
#define M3HL  2816     // tail weights (skewed, q*66), 262 f4
#define LAB1  12312
#define LAB2  12376
#define LW3   12408
#define LAB3  12440
#define LMB2  12441
#define LMB3  12505
#define LM4   12537
#define LMB4  12569
#define MB1F  12572
#define LDSF  12700
// MLP phase reuses f4 [0,1856): X-MLP [64][29]; then H1-MLP [0,1088) s17,
// H2-MLP [1088,1664) s9

typedef const float* fp;

__device__ __forceinline__ float m1s_val(fp m1, int o, int q, int t){
  if(t >= 52) return 0.f;
  int src;
  if(t<8){ int E = (q==0)?0:(8+8*q); src = E + t; }
  else if(t<30){ int d=t-8; int idx = 8*(d>>1)+2*q+(d&1);
                 src = (idx<8) ? (8+idx) : (32+idx); }
  else { int d=t-30; int idx = 8*(d>>1)+2*q+(d&1); src = 120+idx; }
  return m1[o*208 + src];
}
__device__ __forceinline__ float m1k(fp m1, int o, int k){
  return m1s_val(m1, o, k/56, k%56);
}
__device__ __forceinline__ float w1c_val(fp aw1, int o, int q, int h, int d){
  if(d >= 22) return 0.f;
  int idx = 8*(d>>1) + 2*q + (d&1);
  return h ? (aw1[o*264+176+idx] - aw1[o*264+88+idx])
           : (aw1[o*264+idx]     + aw1[o*264+88+idx]);
}
__device__ __forceinline__ float hw1v(fp aw1, int o, int k){
  int h = (k >= 96) ? 1 : 0;
  int kk = k - 96*h;
  int q = kk/24, d = kk%24;
  return (d<22) ? w1c_val(aw1,o,q,h,d) : 0.f;
}

__global__ void din_prep(fp aw1, fp ab1, fp aw2, fp ab2, fp aw3, fp ab3,
                         fp m1,  fp mb1, fp m2,  fp mb2, fp m3,  fp mb3,
                         fp m4,  fp mb4, float* __restrict__ ws){
  int j = blockIdx.x*blockDim.x + threadIdx.x;
  unsigned* wsu = (unsigned*)ws;
  if(j < 6144){ // HW1F: [4n][6t][64][4]
    int frag = j>>2, jr = j&3;
    int lane = frag & 63, nt = frag >> 6;
    int n = nt/6, t = nt%6;
    int o = 16*n + (lane&15);
    int k0 = t*32 + ((lane>>4)<<3) + 2*jr;
    wsu[OFF_HW1F + j] = pack2h(hw1v(aw1,o,k0), hw1v(aw1,o,k0+1));
    return;
  } j -= 6144;
  if(j < 1024){ // AW2F: [2n2][2t2][64][4]
    int frag = j>>2, jr = j&3;
    int lane = frag & 63, nt = frag >> 6;
    int n2 = nt>>1, t2 = nt&1;
    int o = 16*n2 + (lane&15);
    int k0 = t2*32 + ((lane>>4)<<3) + 2*jr;
    wsu[OFF_AW2F + j] = pack2h(aw2[o*64 + k0], aw2[o*64 + k0+1]);
    return;
  } j -= 1024;
  if(j < 258){ // PF
    float v;
    if(j < 64)       v = ab1[j];
    else if(j < 96)  v = ab2[j-64];
    else if(j < 128) v = aw3[j-96];
    else if(j < 129) v = ab3[0];
    else if(j < 193) v = mb2[j-129];
    else if(j < 225) v = mb3[j-193];
    else if(j < 257) v = m4[j-225];
    else             v = mb4[0];
    ws[OFF_PF + j] = v; return;
  } j -= 258;
  if(j < 2){ ws[OFF_PF+258+j] = 0.f; return; } j -= 2;
  if(j < 1024){ // M3H
    int qq = j>>8, rr = j&255, ip = rr>>5, dw = rr&31;
    wsu[OFF_M3H + j] = pack2h(m3[dw*64 + 16*qq + 2*ip], m3[dw*64 + 16*qq + 2*ip+1]);
    return;
  } j -= 1024;
  if(j < 14336){ // MW1F
    int frag = j>>2, jr = j&3;
    int lane = frag & 63, nt = frag >> 6;
    int n = nt/7, t = nt - 7*n;
    int o = 16*n + (lane&15);
    int k0 = t*32 + ((lane>>4)<<3) + 2*jr;
    wsu[OFF_MW1F + j] = pack2h(m1k(m1,o,k0), m1k(m1,o,k0+1));
    return;
  } j -= 14336;
  if(j < 128){ ws[OFF_MB1 + j] = mb1[j]; return; } j -= 128;
  if(j < 4096){ // MW2F
    int frag = j>>2, jr = j&3;
    int lane = frag & 63, nt = frag >> 6;
    int n2 = nt>>2, t2 = nt&3;
    int o = 16*n2 + (lane&15);
    int k0 = t2*32 + ((lane>>4)<<3) + 2*jr;
    wsu[OFF_MW2F + j] = pack2h(m2[o*128 + k0], m2[o*128 + k0+1]);
    return;
  }
}

// DPP quad reduction
template<int CTL>
__device__ __forceinline__ float qp(float v){
  return __uint_as_float((unsigned)__builtin_amdgcn_update_dpp(
      0, (int)__float_as_uint(v), CTL, 0xF, 0xF, true));
}
__device__ __forceinline__ float bsum4(float v){
  v += qp<0xB1>(v);
  v += qp<0x4E>(v);
  return v;
}

__device__ __forceinline__ void ldst16(void* l, const void* g){
  __builtin_amdgcn_global_load_lds(
      (const __attribute__((address_space(1))) unsigned int*)(uintptr_t)g,
      (__attribute__((address_space(3))) unsigned int*)(uintptr_t)l, 16, 0, 0);
}
__device__ __forceinline__ void ldst4(void* l, const void* g){
  __builtin_amdgcn_global_load_lds(
      (const __attribute__((address_space(1))) unsigned int*)(uintptr_t)g,
      (__attribute__((address_space(3))) unsigned int*)(uintptr_t)l, 4, 0, 0);
}

__device__ __forceinline__ void gather_h(const float2* __restrict__ itemp,
                                         const float2* __restrict__ kindp,
                                         int item_idx, const int* __restrict__ kidx,
                                         int q, v2h* f){
  float2 v = itemp[item_idx*4 + q];
  f[0] = pkh(v.x, v.y);
  #pragma unroll
  for(int r=0;r<KIND_LEN;r++){
    int ki = kidx[r];
    float2 w = kindp[ki*4 + q];
    float mx = ki ? w.x : 0.f, my = ki ? w.y : 0.f;
    f[1+r] = pkh(mx, my);
  }
}

__device__ __forceinline__ void write_X(float4* ls4, int base, int wid, int q,
                                        const v2h* f){
  unsigned xd[12];
  #pragma unroll
  for(int r=0;r<11;r++) xd[r] = __builtin_bit_cast(unsigned, f[r]);
  xd[11] = 0;
  uint4* xp = (uint4*)(ls4 + base + wid*13 + 3*q);
  #pragma unroll
  for(int c=0;c<3;c++){
    uint4 t; t.x=xd[4*c]; t.y=xd[4*c+1]; t.z=xd[4*c+2]; t.w=xd[4*c+3];
    xp[c] = t;
  }
}

// 256 threads; 64 samples/block; history AND MLP via MFMA 16x16x32 f16.
// R11 structure: barrier-anchored history (3 barriers/step) — verified best.
__global__ void __launch_bounds__(NTH, 3)
din_main(const int* __restrict__ userid, const int* __restrict__ itemid,
         const int* __restrict__ age,    const int* __restrict__ gen,
         const int* __restrict__ occ,    const int* __restrict__ item_kind,
         const int* __restrict__ his_id, const int* __restrict__ his_kind,
         const float2* __restrict__ user_emb, const float2* __restrict__ item_emb,
         const float2* __restrict__ age_emb,  const float2* __restrict__ gen_emb,
         const float2* __restrict__ occ_emb,  const float2* __restrict__ kind_emb,
         const float* __restrict__ ws, float* __restrict__ out){
  const int tid  = threadIdx.x;
  const int q    = tid & 3;
  const int sl   = (tid & 63) >> 2;
  const int wv   = __builtin_amdgcn_readfirstlane(tid >> 6);
  const int wid  = wv*16 + sl;                 // sample-in-block 0..63
  const int b    = blockIdx.x*SB + wid;
  const int l    = tid & 63;
  const int sr   = wv*16 + (l&15);             // MFMA A-row (sample)
  const int kb   = l >> 4;                     // MFMA K-chunk 0..3

  __shared__ __align__(16) float ls[LDSF];
  float4* ls4 = (float4*)ls;
  const uint4* lsu4 = (const uint4*)ls;
  const float* wsc = ws;
  const float4* ws4 = (const float4*)ws;
  const uint4* wsu4 = (const uint4*)ws;

  // ---- initial async staging: PF(258) + MB1(128) + M3H(skewed) ----
  ldst4(ls + LAB1 + tid, wsc + OFF_PF + tid);
  if(tid < 2)   ldst4(ls + LAB1 + 256 + tid, wsc + OFF_PF + 256 + tid);
  if(tid < 128) ldst4(ls + MB1F + tid, wsc + OFF_MB1 + tid);
  ldst16(ls4 + M3HL + (tid>>6)*66 + (tid&63), ws4 + M3H4 + tid);

  // ---- gather i2 -> X2 (persistent K-tiles 3..5) ----
  {
    v2h i2t[11];
    gather_h(item_emb, kind_emb, itemid[b], item_kind + b*KIND_LEN, q, i2t);
    write_X(ls4, X2B, wid, q, i2t);
  }
  // ---- gather step-0 i1 ----
  v2h i1c[11], i1n[11];
  gather_h(item_emb, kind_emb, his_id[b*HIS_LEN], his_kind + b*HIS_LEN*KIND_LEN,
           q, i1c);

  v2f poolv[11];
  #pragma unroll
  for(int d=0;d<11;d++) poolv[d]=mk2(0.f,0.f);
  v2h i2h[11];
  float2 exr[4];

  __syncthreads();   // staging + X2 drained

  // ---- history: 5 steps, MFMA act-unit ----
  #pragma unroll 1
  for(int s=0;s<5;s++){
    write_X(ls4, X1B, wid, q, i1c);
    __syncthreads();                       // BAR1: X1 ready
    if(s < 4){
      gather_h(item_emb, kind_emb, his_id[b*HIS_LEN+s+1],
               his_kind + (b*HIS_LEN+s+1)*KIND_LEN, q, i1n);
    } else {
      // prefetch MLP inputs under the last step's MFMAs
      gather_h(item_emb, kind_emb, itemid[b], item_kind + b*KIND_LEN, q, i2h);
      const float2* ep = (q==0)? user_emb : (q==1)? age_emb : (q==2)? gen_emb : occ_emb;
      int ei = (q==0)? userid[b] : (q==1)? age[b] : (q==2)? gen[b] : occ[b];
      #pragma unroll
      for(int k=0;k<4;k++) exr[k] = ep[ei*4+k];
    }
    // MFMA1: hidden[64 x 64] = [X1|X2]·HW1 + ab1, relu -> H1 (f16)
    {
      uint4 a1[6];
      #pragma unroll
      for(int t=0;t<3;t++) a1[t]   = lsu4[X1B + sr*13 + 4*t + kb];
      #pragma unroll
      for(int t=0;t<3;t++) a1[3+t] = lsu4[X2B + sr*13 + 4*t + kb];
      _Float16* h1p = (_Float16*)(ls4 + H1B);
      #pragma unroll
      for(int n=0;n<4;n++){
        float bb = ls[LAB1 + 16*n + (l&15)];
        v4f c = {bb,bb,bb,bb};
        #pragma unroll
        for(int t=0;t<6;t++){
          uint4 bw = wsu4[(n*6+t)*64 + l];
          c = __builtin_amdgcn_mfma_f32_16x16x32_f16(C8H(a1[t]), C8H(bw), c, 0, 0, 0);
        }
        #pragma unroll
        for(int i=0;i<4;i++)
          h1p[(16*wv + 4*kb + i)*72 + 16*n + (l&15)] = (_Float16)fmaxf(c[i],0.f);
      }
    }
    __syncthreads();                       // BAR2: H1 ready
    // MFMA2: h2[64 x 32] = H1·AW2 + ab2, relu -> H2 (f32)
    {
      uint4 a2[2];
      #pragma unroll
      for(int t=0;t<2;t++) a2[t] = lsu4[H1B + sr*9 + 4*t + kb];
      float* h2p = (float*)(ls4 + H2B);
      #pragma unroll
      for(int n2=0;n2<2;n2++){
        float bb = ls[LAB2 + 16*n2 + (l&15)];
        v4f c = {bb,bb,bb,bb};
        #pragma unroll
        for(int t=0;t<2;t++){
          uint4 bw = wsu4[AW2F4 + (n2*2+t)*64 + l];
          c = __builtin_amdgcn_mfma_f32_16x16x32_f16(C8H(a2[t]), C8H(bw), c, 0, 0, 0);
        }
        #pragma unroll
        for(int i=0;i<4;i++)
          h2p[(16*wv + 4*kb + i)*36 + 16*n2 + (l&15)] = fmaxf(c[i],0.f);
      }
    }
    __syncthreads();                       // BAR3: H2 ready
    // act tail: sc = w3·H2 + ab3 ; pool += sc * i1^2
    {
      const float4* hr = (const float4*)(ls4 + H2B + wid*9 + 2*q);
      float4 h0 = hr[0], h1v = hr[1];
      float scp = h0.x*ls[LW3+8*q]   + h0.y*ls[LW3+8*q+1]
                + h0.z*ls[LW3+8*q+2] + h0.w*ls[LW3+8*q+3]
                + h1v.x*ls[LW3+8*q+4] + h1v.y*ls[LW3+8*q+5]
                + h1v.z*ls[LW3+8*q+6] + h1v.w*ls[LW3+8*q+7];
      float sc = bsum4(scp) + ls[LAB3];
      #pragma unroll
      for(int j=0;j<11;j++){
        float sx = (float)i1c[j].x, sy = (float)i1c[j].y;
        poolv[j] = __builtin_elementwise_fma(mk2(sx*sc, sy*sc), mk2(sx, sy), poolv[j]);
      }
    }
    #pragma unroll
    for(int j=0;j<11;j++) i1c[j] = i1n[j];
  }

  // ---- MLP phase ----
  v2h fe[26];
  #pragma unroll
  for(int k=0;k<4;k++) fe[k] = pkh(exr[k].x, exr[k].y);
  #pragma unroll
  for(int j=0;j<11;j++) fe[4+j]  = i2h[j];
  #pragma unroll
  for(int j=0;j<11;j++) fe[15+j] = pkh(poolv[j].x, poolv[j].y);

  __syncthreads();   // BAR-M0: all waves past H2 reads; hist regions reusable

  // X-MLP write: [64][29 f4], k-order [q][56]
  {
    unsigned xd[28];
    #pragma unroll
    for(int u=0;u<26;u++) xd[u] = __builtin_bit_cast(unsigned, fe[u]);
    xd[26] = 0; xd[27] = 0;
    uint4* xp = (uint4*)(ls4 + wid*29 + q*7);
    #pragma unroll
    for(int ct=0; ct<7; ct++){
      uint4 t; t.x=xd[4*ct]; t.y=xd[4*ct+1]; t.z=xd[4*ct+2]; t.w=xd[4*ct+3];
      xp[ct] = t;
    }
  }
  __syncthreads();   // BAR-M1: X-MLP complete
  uint4 af[7];
  #pragma unroll
  for(int t=0;t<7;t++) af[t] = lsu4[sr*29 + t*4 + kb];
  __syncthreads();   // BAR-M2: A-frags loaded; [0,1856) reusable

  // MLP1: H1[64x128] = X·W1 + mb1, ReLU
  v4f acc1[8];
  #pragma unroll
  for(int n=0;n<8;n++){
    float bb = ls[MB1F + n*16 + (l&15)];
    v4f c = {bb, bb, bb, bb};
    #pragma unroll
    for(int t=0;t<7;t++){
      uint4 bw = wsu4[MW1F4 + (n*7+t)*64 + l];
      c = __builtin_amdgcn_mfma_f32_16x16x32_f16(C8H(af[t]), C8H(bw), c, 0, 0, 0);
    }
    acc1[n] = c;
  }
  {
    _Float16* h1p = (_Float16*)ls;   // row stride 136 f16 (17 f4)
    #pragma unroll
    for(int n=0;n<8;n++)
      #pragma unroll
      for(int i=0;i<4;i++)
        h1p[(16*wv + 4*kb + i)*136 + 16*n + (l&15)] =
            (_Float16)fmaxf(acc1[n][i], 0.f);
  }
  __syncthreads();   // BAR-M3: H1-MLP ready

  // MLP2: H2[64x64] = H1·W2 + mb2, ReLU
  v4f acc2[4];
  #pragma unroll
  for(int n2=0;n2<4;n2++){
    float bb = ls[LMB2 + n2*16 + (l&15)];
    v4f c = {bb, bb, bb, bb};
    acc2[n2] = c;
  }
  #pragma unroll
  for(int t2=0;t2<4;t2++){
    uint4 aw = lsu4[sr*17 + t2*4 + kb];
    #pragma unroll
    for(int n2=0;n2<4;n2++){
      uint4 bw = wsu4[MW2F4 + (n2*4+t2)*64 + l];
      acc2[n2] = __builtin_amdgcn_mfma_f32_16x16x32_f16(C8H(aw), C8H(bw), acc2[n2], 0, 0, 0);
    }
  }
  {
    _Float16* h2p = (_Float16*)(ls4 + 1088);   // row stride 72 f16 (9 f4)
    #pragma unroll
    for(int n2=0;n2<4;n2++)
      #pragma unroll
      for(int i=0;i<4;i++)
        h2p[(16*wv + 4*kb + i)*72 + 16*n2 + (l&15)] =
            (_Float16)fmaxf(acc2[n2][i], 0.f);
  }
  __syncthreads();   // BAR-M4: H2-MLP ready

  // tail: layers 3+4 (per-sample quad, i-paired fdot2)
  v2h hp3[8];
  {
    const uint4* hr = (const uint4*)(ls4 + 1088 + wid*9 + 2*q);
    uint4 d0 = hr[0], d1 = hr[1];
    hp3[0]=C2H(d0.x); hp3[1]=C2H(d0.y); hp3[2]=C2H(d0.z); hp3[3]=C2H(d0.w);
    hp3[4]=C2H(d1.x); hp3[5]=C2H(d1.y); hp3[6]=C2H(d1.z); hp3[7]=C2H(d1.w);
  }
  float x = ls[LMB4];
  #pragma unroll
  for(int g=0;g<4;g++){
    float a[8];
    #pragma unroll
    for(int j=0;j<8;j++) a[j]=0.f;
    #pragma unroll
    for(int ip=0;ip<8;ip++){
      const uint4* w3p = (const uint4*)(ls4 + M3HL + q*66 + ip*8 + 2*g);
      uint4 b0=w3p[0], b1=w3p[1];
      a[0]=FD2(C2H(b0.x),hp3[ip],a[0]); a[1]=FD2(C2H(b0.y),hp3[ip],a[1]);
      a[2]=FD2(C2H(b0.z),hp3[ip],a[2]); a[3]=FD2(C2H(b0.w),hp3[ip],a[3]);
      a[4]=FD2(C2H(b1.x),hp3[ip],a[4]); a[5]=FD2(C2H(b1.y),hp3[ip],a[5]);
      a[6]=FD2(C2H(b1.z),hp3[ip],a[6]); a[7]=FD2(C2H(b1.w),hp3[ip],a[7]);
    }
    #pragma unroll
    for(int j=0;j<8;j++) a[j] = bsum4(a[j]);
    #pragma unroll
    for(int j=0;j<8;j++)
      x += ls[LM4+8*g+j] * fmaxf(a[j] + ls[LMB3+8*g+j], 0.f);
  }

  if(q==0) out[b] = 1.0f/(1.0f + __expf(-x));
}

extern "C" void kernel_launch(void* const* d_in, const int* in_sizes, int n_in,
                              void* d_out, int out_size, void* d_ws, size_t ws_size,
                              hipStream_t stream){
  const int* userid    = (const int*)d_in[0];
  const int* itemid    = (const int*)d_in[1];
  const int* age       = (const int*)d_in[2];
  const int* gen       = (const int*)d_in[3];
  const int* occ       = (const int*)d_in[4];
  const int* item_kind = (const int*)d_in[5];
  const int* his_id    = (const int*)d_in[6];
  const int* his_kind  = (const int*)d_in[7];
  const float2* user_emb = (const float2*)d_in[8];
  const float2* item_emb = (const float2*)d_in[9];
  const float2* age_emb  = (const float2*)d_in[10];
  const float2* gen_emb  = (const float2*)d_in[11];
  const float2* occ_emb  = (const float2*)d_in[12];
  const float2* kind_emb = (const float2*)d_in[13];
  float* ws = (float*)d_ws;

  din_prep<<<(PREP_N+255)/256, 256, 0, stream>>>(
      (fp)d_in[14], (fp)d_in[15], (fp)d_in[16], (fp)d_in[17], (fp)d_in[18], (fp)d_in[19],
      (fp)d_in[20], (fp)d_in[21], (fp)d_in[22], (fp)d_in[23], (fp)d_in[24], (fp)d_in[25],
      (fp)d_in[26], (fp)d_in[27], ws);

  din_main<<<BATCH/SB, NTH, 0, stream>>>(
      userid, itemid, age, gen, occ, item_kind, his_id, his_kind,
      user_emb, item_emb, age_emb, gen_emb, occ_emb, kind_emb,
      ws, (float*)d_out);
}